// Round 5
// baseline (104.704 us; speedup 1.0000x reference)
//
#include <hip/hip_runtime.h>
#include <stdint.h>

#define NB 32768   // batch
#define NN 128     // stages

typedef __attribute__((ext_vector_type(8))) short bf16x8;
typedef __attribute__((ext_vector_type(4))) float f32x4;

__device__ __forceinline__ short f2bf(float v) {
    uint32_t u = __float_as_uint(v);
    u += 0x7FFF + ((u >> 16) & 1);   // RNE
    return (short)(u >> 16);
}

// One dispatch, one barrier. 1024 blocks x 256 threads.
// block: 64 batch rows x one m-half (16 of 32 m's => 128 of 256 arbiter cols).
//   h = bid>>9 (m-half), row0 = (bid&511)*64; blocks t and t+512 share x rows.
// wave w (0..3): all 64 rows x 32 cols (cols w*32..w*32+31 of the half).
// Math (verified bit-exact vs ref in R2-R4):
//   phi[r][k] = suffix parity of x -> ballot; +-1 bf16 in LDS (XOR-swizzled)
//   x_out = 1-2*sigmoid(prod_kx(phi.Wx+bx))       [B1 GEMM, K=128]
//   raw_y = xo*(S1+phi64*piv) + |xo|*(S2+eps)     [B2 GEMMs, K=64 each]
//   out[m][r] = sigmoid(prod_ky raw_y)
__global__ __launch_bounds__(256, 3) void puf_one(
    const float* __restrict__ x, const float* __restrict__ Wx,
    const float* __restrict__ bx, const float* __restrict__ Wy,
    float* __restrict__ out)
{
    __shared__ __align__(16) uint16_t As[64 * 128];  // 16 KB phi tile
    __shared__ float Sg[64];                         // phi[r][64]

    const int tid = threadIdx.x;
    const int w = tid >> 6, l = tid & 63;
    const int wc = w;                    // col quarter of the 128-col half
    const int l15 = l & 15, l4 = l >> 4;
    const int bid = blockIdx.x;
    const int h = bid >> 9;
    const int row0 = (bid & 511) * 64;

    // ---- per-column constants (L2-hot scatters) ----
    int   cg[2];
    float bxv[2], pivv[2], epsv[2];
#pragma unroll
    for (int cf = 0; cf < 2; ++cf) {
        cg[cf]   = h * 128 + wc * 32 + cf * 16 + l15;
        bxv[cf]  = bx[cg[cf]];
        pivv[cf] = Wy[cg[cf] * 130 + 64];
        epsv[cf] = Wy[cg[cf] * 130 + 129];
    }

    // ---- x rows (coalesced 256B/wave-instr) ----
    float xa[16], xb[16];
#pragma unroll
    for (int i = 0; i < 16; ++i) {
        int grow = row0 + w * 16 + i;
        xa[i] = x[grow * NN + l];
        xb[i] = x[grow * NN + 64 + l];
    }

    // ---- B1 raw weight loads (16B-aligned float4, L2-hot) ----
    f32x4 b1raw[4][2][2];
#pragma unroll
    for (int t = 0; t < 4; ++t)
#pragma unroll
        for (int cf = 0; cf < 2; ++cf) {
            const float* p = Wx + cg[cf] * NN + t * 32 + l4 * 8;
            b1raw[t][cf][0] = *(const f32x4*)p;
            b1raw[t][cf][1] = *(const f32x4*)(p + 4);
        }

    // ---- phi via ballot parity -> As (swizzled +-1 bf16) ----
#pragma unroll
    for (int i = 0; i < 16; ++i) {
        int r = w * 16 + i;
        unsigned long long m0 = __ballot(xa[i] > 0.5f);  // x[r][0..63]
        unsigned long long m1 = __ballot(xb[i] > 0.5f);  // x[r][64..127]
        int onesHi = __popcll(m1);
        int parLo = (__popcll(m0 >> l) + onesHi) & 1;    // parity x[r][l..127]
        int parHi = (__popcll(m1 >> l)) & 1;             // parity x[r][64+l..127]
        int sw = (r & 7) << 3;
        As[r * 128 + (l ^ sw)]        = parLo ? 0xBF80u : 0x3F80u;
        As[r * 128 + (64 + (l ^ sw))] = parHi ? 0xBF80u : 0x3F80u;
        if (l == 0) Sg[r] = (onesHi & 1) ? -1.0f : 1.0f;
    }

    // ---- convert B1 weights to bf16 fragments (frees b1raw) ----
    bf16x8 bfrag[4][2];
#pragma unroll
    for (int t = 0; t < 4; ++t)
#pragma unroll
        for (int cf = 0; cf < 2; ++cf) {
            bf16x8 pk;
#pragma unroll
            for (int e = 0; e < 4; ++e) pk[e]     = f2bf(b1raw[t][cf][0][e]);
#pragma unroll
            for (int e = 0; e < 4; ++e) pk[4 + e] = f2bf(b1raw[t][cf][1][e]);
            bfrag[t][cf] = pk;
        }

    __syncthreads();   // the ONLY barrier

    // ---- issue B2 raw loads now; latency hides under B1 GEMM ----
    float2 s1raw[2][2][4];
    float  s2raw[2][2][8];
#pragma unroll
    for (int t2 = 0; t2 < 2; ++t2)
#pragma unroll
        for (int cf = 0; cf < 2; ++cf) {
            int kk0 = t2 * 32 + l4 * 8;
            const float* p1 = Wy + cg[cf] * 130 + kk0;        // 8B aligned
#pragma unroll
            for (int j = 0; j < 4; ++j) s1raw[t2][cf][j] = *(const float2*)(p1 + 2 * j);
            const float* p2 = Wy + cg[cf] * 130 + 65 + kk0;   // odd offset -> scalars
#pragma unroll
            for (int e = 0; e < 8; ++e) s2raw[t2][cf][e] = p2[e];
        }

    // ---- B1 GEMM: 64 rows x 64 cols/wave, K=128 ----
    const f32x4 zero4 = {0.0f, 0.0f, 0.0f, 0.0f};
    f32x4 acc1[4][2];
#pragma unroll
    for (int a = 0; a < 4; ++a)
#pragma unroll
        for (int b = 0; b < 2; ++b) acc1[a][b] = zero4;

    __builtin_amdgcn_s_setprio(1);
#pragma unroll
    for (int t = 0; t < 4; ++t) {
        int k = t * 32 + l4 * 8;
        bf16x8 af[4];
#pragma unroll
        for (int rf = 0; rf < 4; ++rf) {
            int r = rf * 16 + l15;
            af[rf] = *(const bf16x8*)&As[r * 128 + ((k & 64) | ((k & 63) ^ ((r & 7) << 3)))];
        }
#pragma unroll
        for (int rf = 0; rf < 4; ++rf)
#pragma unroll
            for (int cf = 0; cf < 2; ++cf)
                acc1[rf][cf] = __builtin_amdgcn_mfma_f32_16x16x32_bf16(af[rf], bfrag[t][cf], acc1[rf][cf], 0, 0, 0);
    }
    __builtin_amdgcn_s_setprio(0);

    // ---- convert B2 weights to bf16 fragments (frees raws) ----
    bf16x8 b1f[2][2], b2f[2][2];
#pragma unroll
    for (int t2 = 0; t2 < 2; ++t2)
#pragma unroll
        for (int cf = 0; cf < 2; ++cf) {
            bf16x8 pa, pb;
#pragma unroll
            for (int j = 0; j < 4; ++j) {
                pa[2 * j]     = f2bf(s1raw[t2][cf][j].x);
                pa[2 * j + 1] = f2bf(s1raw[t2][cf][j].y);
            }
#pragma unroll
            for (int e = 0; e < 8; ++e) pb[e] = f2bf(s2raw[t2][cf][e]);
            b1f[t2][cf] = pa;
            b2f[t2][cf] = pb;
        }

    // ---- B1 epilogue fully in registers: xo[rf][cf][q] ----
    float xo[4][2][4];
#pragma unroll
    for (int rf = 0; rf < 4; ++rf)
#pragma unroll
        for (int cf = 0; cf < 2; ++cf) {
            float p[4];
#pragma unroll
            for (int q = 0; q < 4; ++q) p[q] = acc1[rf][cf][q] + bxv[cf];
#pragma unroll
            for (int q = 0; q < 4; ++q) {
                p[q] *= __shfl_xor(p[q], 1);
                p[q] *= __shfl_xor(p[q], 2);
                p[q] *= __shfl_xor(p[q], 4);
            }
#pragma unroll
            for (int q = 0; q < 4; ++q) {
                float sig = 1.0f / (1.0f + __expf(-p[q]));
                xo[rf][cf][q] = 1.0f - 2.0f * sig;
            }
        }

    // ---- B2 GEMMs: S1 (k<64) and S2 (k>=64) ----
    f32x4 aS1[4][2], aS2[4][2];
#pragma unroll
    for (int a = 0; a < 4; ++a)
#pragma unroll
        for (int b = 0; b < 2; ++b) { aS1[a][b] = zero4; aS2[a][b] = zero4; }

    __builtin_amdgcn_s_setprio(1);
#pragma unroll
    for (int t2 = 0; t2 < 2; ++t2) {
        int kk = t2 * 32 + l4 * 8;
        bf16x8 af1[4], af2[4];
#pragma unroll
        for (int rf = 0; rf < 4; ++rf) {
            int r = rf * 16 + l15;
            int swr = (r & 7) << 3;
            af1[rf] = *(const bf16x8*)&As[r * 128 + (kk ^ swr)];
            af2[rf] = *(const bf16x8*)&As[r * 128 + (64 | (kk ^ swr))];
        }
#pragma unroll
        for (int rf = 0; rf < 4; ++rf)
#pragma unroll
            for (int cf = 0; cf < 2; ++cf) {
                aS1[rf][cf] = __builtin_amdgcn_mfma_f32_16x16x32_bf16(af1[rf], b1f[t2][cf], aS1[rf][cf], 0, 0, 0);
                aS2[rf][cf] = __builtin_amdgcn_mfma_f32_16x16x32_bf16(af2[rf], b2f[t2][cf], aS2[rf][cf], 0, 0, 0);
            }
    }
    __builtin_amdgcn_s_setprio(0);

    // ---- B2 epilogue: combine, product over ky, sigmoid, store ----
#pragma unroll
    for (int rf = 0; rf < 4; ++rf)
#pragma unroll
        for (int cf = 0; cf < 2; ++cf) {
            float p[4];
#pragma unroll
            for (int q = 0; q < 4; ++q) {
                int r = rf * 16 + l4 * 4 + q;
                float xov = xo[rf][cf][q];
                float axo = fabsf(xov);
                float s1 = aS1[rf][cf][q] + Sg[r] * pivv[cf];
                float s2 = aS2[rf][cf][q] + epsv[cf];
                p[q] = xov * s1 + axo * s2;
            }
#pragma unroll
            for (int q = 0; q < 4; ++q) {
                p[q] *= __shfl_xor(p[q], 1);
                p[q] *= __shfl_xor(p[q], 2);
                p[q] *= __shfl_xor(p[q], 4);
            }
            if ((l & 7) == 0) {
                f32x4 o;
#pragma unroll
                for (int q = 0; q < 4; ++q) o[q] = 1.0f / (1.0f + __expf(-p[q]));
                int m = wc * 4 + cf * 2 + (l15 >> 3);
                *(f32x4*)&out[(h * 16 + m) * NB + row0 + rf * 16 + l4 * 4] = o;
            }
        }
}

extern "C" void kernel_launch(void* const* d_in, const int* in_sizes, int n_in,
                              void* d_out, int out_size, void* d_ws, size_t ws_size,
                              hipStream_t stream) {
    const float* x  = (const float*)d_in[0];
    const float* Wx = (const float*)d_in[1];
    const float* bx = (const float*)d_in[2];
    const float* Wy = (const float*)d_in[3];
    float* out = (float*)d_out;
    (void)d_ws; (void)ws_size;

    puf_one<<<dim3(1024), dim3(256), 0, stream>>>(x, Wx, bx, Wy, out);
}

// Round 7
// 86.914 us; speedup vs baseline: 1.2047x; 1.2047x over previous
//
#include <hip/hip_runtime.h>
#include <stdint.h>

#define NB 32768   // batch
#define NN 128     // stages

typedef __attribute__((ext_vector_type(8))) short bf16x8;
typedef __attribute__((ext_vector_type(4))) float f32x4;

__device__ __forceinline__ short f2bf(float v) {
    uint32_t u = __float_as_uint(v);
    u += 0x7FFF + ((u >> 16) & 1);   // RNE
    return (short)(u >> 16);
}

// d_ws layout (Wc, uint16 units):
//  chunks are bf16x8 (16B), chunk index ci -> shorts [ci*8, ci*8+8)
//  B1 stream : ci = (c16*4 + t )*64 + l, c16<16, t<4 :
//              e -> Wx[(c16*16+(l&15))*128 + t*32 + (l>>4)*8 + e]
//  S1 stream : ci = 4096 + (c16*2 + t2)*64 + l :
//              e -> Wy[col*130 + t2*32 + (l>>4)*8 + e]          (k_abs = kk)
//  S2 stream : ci = 6144 + (c16*2 + t2)*64 + l :
//              e -> Wy[col*130 + 65 + t2*32 + (l>>4)*8 + e]     (k_abs = 64+kk)
//  consts    : floats at short-offset 65536: [0,256)=bx, [256,512)=Wy[c][64],
//              [512,768)=Wy[c][129]
__global__ void puf_prep(const float* __restrict__ Wx, const float* __restrict__ bx,
                         const float* __restrict__ Wy, uint16_t* __restrict__ Wc) {
    int gid = blockIdx.x * 256 + threadIdx.x;   // 8960 items
    if (gid < 8192) {
        int l = gid & 63;
        int l15 = l & 15, k8 = (l >> 4) * 8;
        const float* src;
        if (gid < 4096) {
            int c16 = gid >> 8, t = (gid >> 6) & 3;
            src = Wx + (c16 * 16 + l15) * NN + t * 32 + k8;
        } else if (gid < 6144) {
            int j = gid - 4096;
            int c16 = j >> 7, t2 = (j >> 6) & 1;
            src = Wy + (c16 * 16 + l15) * 130 + t2 * 32 + k8;
        } else {
            int j = gid - 6144;
            int c16 = j >> 7, t2 = (j >> 6) & 1;
            src = Wy + (c16 * 16 + l15) * 130 + 65 + t2 * 32 + k8;
        }
        bf16x8 pk;
#pragma unroll
        for (int e = 0; e < 8; ++e) pk[e] = f2bf(src[e]);
        *(bf16x8*)&Wc[gid * 8] = pk;
    } else if (gid < 8960) {
        int j = gid - 8192;                 // 0..767
        int c = j & 255, sel = j >> 8;
        float v = (sel == 0) ? bx[c] : ((sel == 1) ? Wy[c * 130 + 64] : Wy[c * 130 + 129]);
        ((float*)(Wc + 65536))[j] = v;
    }
}

// 2048 blocks x 256 threads. Block: rg = bid&511 (64 batch rows), cg = bid>>9
// (64 of 256 arbiter cols). Blocks rg, rg+512, rg+1024, rg+1536 share x rows
// and land on the same XCD (512 % 8 == 0) -> x is L2-hot for 3 of 4 reads.
// Wave w: 64 rows x 16 cols (c16 = cg*4+w); m outputs c16*2, c16*2+1.
__global__ __launch_bounds__(256, 4) void puf_main(
    const float* __restrict__ x, const uint16_t* __restrict__ Wc,
    float* __restrict__ out)
{
    __shared__ __align__(16) uint16_t As[64 * 128];  // 16 KB phi (swizzled +-1)
    __shared__ float Sg[64];                         // phi[r][64]

    const int tid = threadIdx.x;
    const int w = tid >> 6, l = tid & 63;
    const int l15 = l & 15, l4 = l >> 4;
    const int bid = blockIdx.x;
    const int rg = bid & 511, cg = bid >> 9;
    const int row0 = rg * 64;
    const int c16 = cg * 4 + w;

    const bf16x8* wc8 = (const bf16x8*)Wc;
    const float*  cw  = (const float*)(Wc + 65536);

    // ---- weight fragments: pre-packed, one coalesced 16B load each ----
    bf16x8 fB1[4], fS1[2], fS2[2];
#pragma unroll
    for (int t = 0; t < 4; ++t)  fB1[t]  = wc8[(c16 * 4 + t) * 64 + l];
#pragma unroll
    for (int t2 = 0; t2 < 2; ++t2) fS1[t2] = wc8[4096 + (c16 * 2 + t2) * 64 + l];
#pragma unroll
    for (int t2 = 0; t2 < 2; ++t2) fS2[t2] = wc8[6144 + (c16 * 2 + t2) * 64 + l];
    const int col = c16 * 16 + l15;
    const float bxv = cw[col], piv = cw[256 + col], eps = cw[512 + col];

    // ---- x rows (coalesced) ----
    float xa[16], xb[16];
#pragma unroll
    for (int i = 0; i < 16; ++i) {
        int grow = row0 + w * 16 + i;
        xa[i] = x[grow * NN + l];
        xb[i] = x[grow * NN + 64 + l];
    }

    // ---- phi via ballot parity -> As (XOR-swizzled +-1 bf16) ----
#pragma unroll
    for (int i = 0; i < 16; ++i) {
        int r = w * 16 + i;
        unsigned long long m0 = __ballot(xa[i] > 0.5f);  // x[r][0..63]
        unsigned long long m1 = __ballot(xb[i] > 0.5f);  // x[r][64..127]
        int onesHi = __popcll(m1);
        int parLo = (__popcll(m0 >> l) + onesHi) & 1;    // parity x[r][l..127]
        int parHi = (__popcll(m1 >> l)) & 1;             // parity x[r][64+l..127]
        int sw = (r & 7) << 3;
        As[r * 128 + (l ^ sw)]        = parLo ? 0xBF80u : 0x3F80u;
        As[r * 128 + (64 + (l ^ sw))] = parHi ? 0xBF80u : 0x3F80u;
        if (l == 0) Sg[r] = (onesHi & 1) ? -1.0f : 1.0f;
    }
    __syncthreads();   // the only barrier

    // ---- B1 GEMM: 64 rows x 16 cols, K=128 ----
    const f32x4 zero4 = {0.0f, 0.0f, 0.0f, 0.0f};
    f32x4 acc1[4];
#pragma unroll
    for (int a = 0; a < 4; ++a) acc1[a] = zero4;

    __builtin_amdgcn_s_setprio(1);
#pragma unroll
    for (int t = 0; t < 4; ++t) {
        int k = t * 32 + l4 * 8;
#pragma unroll
        for (int rf = 0; rf < 4; ++rf) {
            int r = rf * 16 + l15;
            bf16x8 af = *(const bf16x8*)&As[r * 128 + ((k & 64) | ((k & 63) ^ ((r & 7) << 3)))];
            acc1[rf] = __builtin_amdgcn_mfma_f32_16x16x32_bf16(af, fB1[t], acc1[rf], 0, 0, 0);
        }
    }
    __builtin_amdgcn_s_setprio(0);

    // ---- B1 epilogue in registers: xo[rf][q] ----
    float xo[4][4];
#pragma unroll
    for (int rf = 0; rf < 4; ++rf) {
        float p[4];
#pragma unroll
        for (int q = 0; q < 4; ++q) p[q] = acc1[rf][q] + bxv;
#pragma unroll
        for (int q = 0; q < 4; ++q) {
            p[q] *= __shfl_xor(p[q], 1);
            p[q] *= __shfl_xor(p[q], 2);
            p[q] *= __shfl_xor(p[q], 4);
        }
#pragma unroll
        for (int q = 0; q < 4; ++q) {
            float sig = 1.0f / (1.0f + __expf(-p[q]));
            xo[rf][q] = 1.0f - 2.0f * sig;
        }
    }

    // ---- B2 GEMMs: S1 (k<64) and S2 (k>=64) ----
    f32x4 aS1[4], aS2[4];
#pragma unroll
    for (int a = 0; a < 4; ++a) { aS1[a] = zero4; aS2[a] = zero4; }

    __builtin_amdgcn_s_setprio(1);
#pragma unroll
    for (int t2 = 0; t2 < 2; ++t2) {
        int kk = t2 * 32 + l4 * 8;
#pragma unroll
        for (int rf = 0; rf < 4; ++rf) {
            int r = rf * 16 + l15;
            int swr = (r & 7) << 3;
            bf16x8 af1 = *(const bf16x8*)&As[r * 128 + (kk ^ swr)];
            bf16x8 af2 = *(const bf16x8*)&As[r * 128 + (64 | (kk ^ swr))];
            aS1[rf] = __builtin_amdgcn_mfma_f32_16x16x32_bf16(af1, fS1[t2], aS1[rf], 0, 0, 0);
            aS2[rf] = __builtin_amdgcn_mfma_f32_16x16x32_bf16(af2, fS2[t2], aS2[rf], 0, 0, 0);
        }
    }
    __builtin_amdgcn_s_setprio(0);

    // ---- B2 epilogue: combine, product over ky, sigmoid, store ----
#pragma unroll
    for (int rf = 0; rf < 4; ++rf) {
        float p[4];
#pragma unroll
        for (int q = 0; q < 4; ++q) {
            int r = rf * 16 + l4 * 4 + q;
            float xov = xo[rf][q];
            float s1 = aS1[rf][q] + Sg[r] * piv;
            float s2 = aS2[rf][q] + eps;
            p[q] = xov * s1 + fabsf(xov) * s2;
        }
#pragma unroll
        for (int q = 0; q < 4; ++q) {
            p[q] *= __shfl_xor(p[q], 1);
            p[q] *= __shfl_xor(p[q], 2);
            p[q] *= __shfl_xor(p[q], 4);
        }
        if ((l & 7) == 0) {
            f32x4 o;
#pragma unroll
            for (int q = 0; q < 4; ++q) o[q] = 1.0f / (1.0f + __expf(-p[q]));
            int m = c16 * 2 + (l15 >> 3);
            *(f32x4*)&out[m * NB + row0 + rf * 16 + l4 * 4] = o;
        }
    }
}

extern "C" void kernel_launch(void* const* d_in, const int* in_sizes, int n_in,
                              void* d_out, int out_size, void* d_ws, size_t ws_size,
                              hipStream_t stream) {
    const float* x  = (const float*)d_in[0];
    const float* Wx = (const float*)d_in[1];
    const float* bx = (const float*)d_in[2];
    const float* Wy = (const float*)d_in[3];
    float* out = (float*)d_out;
    uint16_t* Wc = (uint16_t*)d_ws;   // ~134 KB used

    puf_prep<<<dim3(35), dim3(256), 0, stream>>>(Wx, bx, Wy, Wc);
    puf_main<<<dim3(2048), dim3(256), 0, stream>>>(x, Wc, out);
}

// Round 8
// 85.146 us; speedup vs baseline: 1.2297x; 1.0208x over previous
//
#include <hip/hip_runtime.h>
#include <stdint.h>

#define NB 32768   // batch
#define NN 128     // stages

typedef __attribute__((ext_vector_type(8))) short bf16x8;
typedef __attribute__((ext_vector_type(4))) float f32x4;

__device__ __forceinline__ short f2bf(float v) {
    uint32_t u = __float_as_uint(v);
    u += 0x7FFF + ((u >> 16) & 1);   // RNE
    return (short)(u >> 16);
}

// d_ws layout:
//  shorts [0, 8192*8)      : weight fragment streams (bf16x8 chunks), as R7:
//     B1: ci=(c16*4+t)*64+l ; S1: ci=4096+(c16*2+t2)*64+l ; S2: ci=6144+...
//  shorts [65536, 65536+1536): float consts: [0,256)=bx, [256,512)=Wy[c][64],
//                              [512,768)=Wy[c][129]
//  bytes  [196608, 327680) : Pg[32768] float  = phi[r][64] (+-1.0f)
//  bytes  [524288, +8.39MB): Pf: phi A-fragments, bf16x8 chunk index
//                            ((rb*4 + t)*4 + rf)*64 + l   (rb<512 row-blocks)
#define WS_CONST_SHORTOFF 65536
#define WS_PG_BYTEOFF     196608
#define WS_PF_BYTEOFF     524288

// 547 blocks x 256. Blocks 0..511: phi part (64 rows each). 512..546: weights.
__global__ void puf_prep(const float* __restrict__ x, const float* __restrict__ Wx,
                         const float* __restrict__ bx, const float* __restrict__ Wy,
                         uint16_t* __restrict__ Wc) {
    const int bid = blockIdx.x, tid = threadIdx.x;
    if (bid < 512) {
        __shared__ __align__(16) uint16_t As[64 * 128];
        __shared__ float Sg[64];
        const int w = tid >> 6, l = tid & 63;
        const int l15 = l & 15, l4 = l >> 4;
        const int row0 = bid * 64;

        float xa[16], xb[16];
#pragma unroll
        for (int i = 0; i < 16; ++i) {
            int grow = row0 + w * 16 + i;
            xa[i] = x[grow * NN + l];
            xb[i] = x[grow * NN + 64 + l];
        }
#pragma unroll
        for (int i = 0; i < 16; ++i) {
            int r = w * 16 + i;
            unsigned long long m0 = __ballot(xa[i] > 0.5f);  // x[r][0..63]
            unsigned long long m1 = __ballot(xb[i] > 0.5f);  // x[r][64..127]
            int onesHi = __popcll(m1);
            int parLo = (__popcll(m0 >> l) + onesHi) & 1;    // parity x[r][l..127]
            int parHi = (__popcll(m1 >> l)) & 1;             // parity x[r][64+l..127]
            int sw = (r & 7) << 3;
            As[r * 128 + (l ^ sw)]        = parLo ? 0xBF80u : 0x3F80u;
            As[r * 128 + (64 + (l ^ sw))] = parHi ? 0xBF80u : 0x3F80u;
            if (l == 0) Sg[r] = (onesHi & 1) ? -1.0f : 1.0f;
        }
        __syncthreads();

        // export A-fragments: wave w handles K-tile t = w
        bf16x8* Pf8 = (bf16x8*)((char*)Wc + WS_PF_BYTEOFF);
        const int k = w * 32 + l4 * 8;
#pragma unroll
        for (int rf = 0; rf < 4; ++rf) {
            int r = rf * 16 + l15;
            bf16x8 af = *(const bf16x8*)&As[r * 128 + ((k & 64) | ((k & 63) ^ ((r & 7) << 3)))];
            Pf8[((bid * 4 + w) * 4 + rf) * 64 + l] = af;
        }
        float* Pg = (float*)((char*)Wc + WS_PG_BYTEOFF);
        if (tid < 64) Pg[row0 + tid] = Sg[tid];
    } else {
        int gid = (bid - 512) * 256 + tid;   // 8960 items
        if (gid < 8192) {
            int l = gid & 63;
            int l15 = l & 15, k8 = (l >> 4) * 8;
            const float* src;
            if (gid < 4096) {
                int c16 = gid >> 8, t = (gid >> 6) & 3;
                src = Wx + (c16 * 16 + l15) * NN + t * 32 + k8;
            } else if (gid < 6144) {
                int j = gid - 4096;
                int c16 = j >> 7, t2 = (j >> 6) & 1;
                src = Wy + (c16 * 16 + l15) * 130 + t2 * 32 + k8;
            } else {
                int j = gid - 6144;
                int c16 = j >> 7, t2 = (j >> 6) & 1;
                src = Wy + (c16 * 16 + l15) * 130 + 65 + t2 * 32 + k8;
            }
            bf16x8 pk;
#pragma unroll
            for (int e = 0; e < 8; ++e) pk[e] = f2bf(src[e]);
            *(bf16x8*)&Wc[gid * 8] = pk;
        } else if (gid < 8960) {
            int j = gid - 8192;                 // 0..767
            int c = j & 255, sel = j >> 8;
            float v = (sel == 0) ? bx[c] : ((sel == 1) ? Wy[c * 130 + 64] : Wy[c * 130 + 129]);
            ((float*)(Wc + WS_CONST_SHORTOFF))[j] = v;
        }
    }
}

// 2048 blocks x 256 threads, NO LDS, NO barrier. Block: rg=bid&511 (64 rows),
// cg=bid>>9 (64 of 256 cols). rg,rg+512,... share A-frags on same XCD.
// Wave w: 64 rows x 16 cols (c16=cg*4+w); m outputs c16*2, c16*2+1.
__global__ __launch_bounds__(256, 3) void puf_main(
    const uint16_t* __restrict__ Wc, float* __restrict__ out)
{
    const int tid = threadIdx.x;
    const int w = tid >> 6, l = tid & 63;
    const int l15 = l & 15, l4 = l >> 4;
    const int bid = blockIdx.x;
    const int rg = bid & 511, cg = bid >> 9;
    const int row0 = rg * 64;
    const int c16 = cg * 4 + w;

    const bf16x8* wc8 = (const bf16x8*)Wc;
    const float*  cw  = (const float*)(Wc + WS_CONST_SHORTOFF);
    const float*  Pg  = (const float*)((const char*)Wc + WS_PG_BYTEOFF);
    const bf16x8* Pf8 = (const bf16x8*)((const char*)Wc + WS_PF_BYTEOFF);

    // ---- A-fragments for this row-block (held across B1 and B2) ----
    bf16x8 aF[4][4];
#pragma unroll
    for (int t = 0; t < 4; ++t)
#pragma unroll
        for (int rf = 0; rf < 4; ++rf)
            aF[t][rf] = Pf8[((rg * 4 + t) * 4 + rf) * 64 + l];

    // ---- weight fragments + constants ----
    bf16x8 fB1[4], fS1[2], fS2[2];
#pragma unroll
    for (int t = 0; t < 4; ++t)  fB1[t]  = wc8[(c16 * 4 + t) * 64 + l];
#pragma unroll
    for (int t2 = 0; t2 < 2; ++t2) fS1[t2] = wc8[4096 + (c16 * 2 + t2) * 64 + l];
#pragma unroll
    for (int t2 = 0; t2 < 2; ++t2) fS2[t2] = wc8[6144 + (c16 * 2 + t2) * 64 + l];
    const int col = c16 * 16 + l15;
    const float bxv = cw[col], piv = cw[256 + col], eps = cw[512 + col];

    // phi[r][64] for this thread's accumulator rows
    f32x4 sg[4];
#pragma unroll
    for (int rf = 0; rf < 4; ++rf)
        sg[rf] = *(const f32x4*)&Pg[row0 + rf * 16 + l4 * 4];

    // ---- B1 GEMM: K=128 ----
    const f32x4 zero4 = {0.0f, 0.0f, 0.0f, 0.0f};
    f32x4 acc1[4];
#pragma unroll
    for (int a = 0; a < 4; ++a) acc1[a] = zero4;

    __builtin_amdgcn_s_setprio(1);
#pragma unroll
    for (int t = 0; t < 4; ++t)
#pragma unroll
        for (int rf = 0; rf < 4; ++rf)
            acc1[rf] = __builtin_amdgcn_mfma_f32_16x16x32_bf16(aF[t][rf], fB1[t], acc1[rf], 0, 0, 0);
    __builtin_amdgcn_s_setprio(0);

    // ---- B1 epilogue in registers: xo[rf][q] ----
    float xo[4][4];
#pragma unroll
    for (int rf = 0; rf < 4; ++rf) {
        float p[4];
#pragma unroll
        for (int q = 0; q < 4; ++q) p[q] = acc1[rf][q] + bxv;
#pragma unroll
        for (int q = 0; q < 4; ++q) {
            p[q] *= __shfl_xor(p[q], 1);
            p[q] *= __shfl_xor(p[q], 2);
            p[q] *= __shfl_xor(p[q], 4);
        }
#pragma unroll
        for (int q = 0; q < 4; ++q) {
            float sig = 1.0f / (1.0f + __expf(-p[q]));
            xo[rf][q] = 1.0f - 2.0f * sig;
        }
    }

    // ---- B2 GEMMs: S1 uses tiles 0,1 (k<64); S2 uses tiles 2,3 (k>=64) ----
    f32x4 aS1[4], aS2[4];
#pragma unroll
    for (int a = 0; a < 4; ++a) { aS1[a] = zero4; aS2[a] = zero4; }

    __builtin_amdgcn_s_setprio(1);
#pragma unroll
    for (int t2 = 0; t2 < 2; ++t2)
#pragma unroll
        for (int rf = 0; rf < 4; ++rf) {
            aS1[rf] = __builtin_amdgcn_mfma_f32_16x16x32_bf16(aF[t2][rf],     fS1[t2], aS1[rf], 0, 0, 0);
            aS2[rf] = __builtin_amdgcn_mfma_f32_16x16x32_bf16(aF[2 + t2][rf], fS2[t2], aS2[rf], 0, 0, 0);
        }
    __builtin_amdgcn_s_setprio(0);

    // ---- B2 epilogue: combine, product over ky, sigmoid, store ----
#pragma unroll
    for (int rf = 0; rf < 4; ++rf) {
        float p[4];
#pragma unroll
        for (int q = 0; q < 4; ++q) {
            float xov = xo[rf][q];
            float s1 = aS1[rf][q] + sg[rf][q] * piv;
            float s2 = aS2[rf][q] + eps;
            p[q] = xov * s1 + fabsf(xov) * s2;
        }
#pragma unroll
        for (int q = 0; q < 4; ++q) {
            p[q] *= __shfl_xor(p[q], 1);
            p[q] *= __shfl_xor(p[q], 2);
            p[q] *= __shfl_xor(p[q], 4);
        }
        if ((l & 7) == 0) {
            f32x4 o;
#pragma unroll
            for (int q = 0; q < 4; ++q) o[q] = 1.0f / (1.0f + __expf(-p[q]));
            int m = c16 * 2 + (l15 >> 3);
            *(f32x4*)&out[m * NB + row0 + rf * 16 + l4 * 4] = o;
        }
    }
}

extern "C" void kernel_launch(void* const* d_in, const int* in_sizes, int n_in,
                              void* d_out, int out_size, void* d_ws, size_t ws_size,
                              hipStream_t stream) {
    const float* x  = (const float*)d_in[0];
    const float* Wx = (const float*)d_in[1];
    const float* bx = (const float*)d_in[2];
    const float* Wy = (const float*)d_in[3];
    float* out = (float*)d_out;
    uint16_t* Wc = (uint16_t*)d_ws;   // ~8.9 MB used

    puf_prep<<<dim3(547), dim3(256), 0, stream>>>(x, Wx, bx, Wy, Wc);
    puf_main<<<dim3(2048), dim3(256), 0, stream>>>(Wc, out);
}